// Round 1
// baseline (792.433 us; speedup 1.0000x reference)
//
#include <hip/hip_runtime.h>
#include <stdint.h>

typedef __attribute__((ext_vector_type(8))) __bf16 bf16x8;
typedef __attribute__((ext_vector_type(16))) float f32x16;

constexpr int CIN = 256, COUT = 256, HH = 512, WW = 512;
constexpr int BC = 16;     // input channels per K-iteration
constexpr int NCB = CIN / BC;   // 16 channel blocks
constexpr int CPAD = 20;   // LDS channel stride (40B -> bank stride 10 -> uniform 4 dwords/bank, conflict-free)
constexpr int MT = 128;    // out-channels per workgroup
constexpr int TY = 8, TX = 32;  // pixel tile: 8 rows x 32 cols

__device__ __forceinline__ unsigned short f2bf(float f) {
    union { float f; unsigned int u; } v; v.f = f;
    return (unsigned short)((v.u + 0x7fffu + ((v.u >> 16) & 1u)) >> 16);  // RNE
}

__device__ __forceinline__ bf16x8 ldsfrag(const unsigned short* p) {
    // 8-byte-aligned LDS loads (base stride is 40B, +0/+16 for c-half)
    union { unsigned long long u[2]; bf16x8 v; } r;
    r.u[0] = *reinterpret_cast<const unsigned long long*>(p);
    r.u[1] = *reinterpret_cast<const unsigned long long*>(p + 4);
    return r.v;
}

// ============ NEW PATH: pre-transformed operands in ws ============
// wt2 layout: [cb][tap][k][ci] bf16  (144 * 256 * 16) — c-blocked so a 128-row,
// 16-ch weight panel is one contiguous 4KB run per tap (coalesced 16B chunks).
__global__ void wt_transform2(const float* __restrict__ w, unsigned short* __restrict__ wt2) {
    const int cbtap = blockIdx.x;              // [0, 144)
    const int cb = cbtap / 9, tap = cbtap - cb * 9;
    #pragma unroll 4
    for (int e = threadIdx.x; e < 4096; e += 256) {
        const int k = e >> 4, ci = e & 15;
        wt2[cbtap * 4096 + e] = f2bf(w[(k * CIN + cb * BC + ci) * 9 + tap]);
    }
}

// xb layout: [cb][y][x][ci] bf16 (channel-blocked NHWC) — 16-ch slice of any pixel
// run is contiguous; a wave's staging row is one 1KB contiguous load.
__global__ __launch_bounds__(256)
void x_transform(const float* __restrict__ x, unsigned short* __restrict__ xb) {
    __shared__ unsigned short Xl[64][264];     // pad 264: phase-2 b128 reads conflict-free
    const int y  = blockIdx.x >> 3;
    const int x0 = (blockIdx.x & 7) * 64;
    #pragma unroll
    for (int q = threadIdx.x; q < 4096; q += 256) {   // 256c x 16 float4 along x
        const int c = q >> 4, p4 = (q & 15) << 2;
        const float4 v = *reinterpret_cast<const float4*>(
            x + ((long long)c * HH + y) * WW + x0 + p4);
        Xl[p4 + 0][c] = f2bf(v.x);
        Xl[p4 + 1][c] = f2bf(v.y);
        Xl[p4 + 2][c] = f2bf(v.z);
        Xl[p4 + 3][c] = f2bf(v.w);
    }
    __syncthreads();
    #pragma unroll
    for (int q = threadIdx.x; q < 2048; q += 256) {   // 16B chunks: (cb, px, half)
        const int cb = q >> 7, rem = q & 127, px = rem >> 1, h = rem & 1;
        const int4 v = *reinterpret_cast<const int4*>(&Xl[px][cb * 16 + h * 8]);
        *reinterpret_cast<int4*>(
            xb + (((long long)cb * HH + y) * WW + x0 + px) * 16 + h * 8) = v;
    }
}

__global__ __launch_bounds__(256, 2)
void conv_mfma2(const unsigned short* __restrict__ xb, const unsigned short* __restrict__ wt2,
                float* __restrict__ out) {
    __shared__ unsigned short Wlds[9][MT][CPAD];          // 46080 B
    __shared__ unsigned short Xt[TY + 2][TX + 2][CPAD];   // 13600 B  (total 59680 -> 2 blocks/CU)

    const int bid = blockIdx.x;
    const int k0 = (bid & 1) * MT;          // pair M-blocks of same tile for input reuse
    const int tile = bid >> 1;
    const int x0 = (tile & 15) * TX;
    const int y0 = (tile >> 4) * TY;

    const int tid = threadIdx.x;
    const int lane = tid & 63;
    const int wave = tid >> 6;
    const int wm = wave & 1;                // m-half (64 out-channels)
    const int wn = wave >> 1;               // n-half (4 pixel rows)
    const int ln31 = lane & 31;
    const int lh8 = (lane >> 5) * 8;        // k-offset of this lane's frag

    f32x16 acc[2][4];
    #pragma unroll
    for (int i = 0; i < 2; ++i)
        #pragma unroll
        for (int j = 0; j < 4; ++j)
            #pragma unroll
            for (int r = 0; r < 16; ++r) acc[i][j][r] = 0.f;

    for (int cb = 0; cb < NCB; ++cb) {
        // ---- stage weight panel: contiguous 16B chunks, e = (tap, k, half)
        #pragma unroll
        for (int e = tid; e < 9 * 256; e += 256) {
            const int tap = e >> 8;
            const int kk = (e >> 1) & 127;
            const int h = e & 1;
            const int4 v = *reinterpret_cast<const int4*>(
                wt2 + (((cb * 9 + tap) * 256 + k0 + kk) << 4) + h * 8);
            unsigned long long* d = reinterpret_cast<unsigned long long*>(&Wlds[tap][kk][h * 8]);
            const unsigned long long* s2 = reinterpret_cast<const unsigned long long*>(&v);
            d[0] = s2[0]; d[1] = s2[1];
        }

        // ---- stage input slab from blocked-NHWC bf16: wave w does rows w, w+4, w+8
        for (int rr = wave; rr < TY + 2; rr += 4) {
            const int yy = y0 - 1 + rr;
            const bool rowok = ((unsigned)yy < (unsigned)HH);
            const int xi = lane >> 1, h = lane & 1;
            const int gx = x0 - 1 + xi;
            int4 v; v.x = v.y = v.z = v.w = 0;
            if (rowok && (unsigned)gx < (unsigned)WW)
                v = *reinterpret_cast<const int4*>(
                    xb + (((cb * HH + yy) * WW + gx) << 4) + h * 8);
            unsigned long long* d = reinterpret_cast<unsigned long long*>(&Xt[rr][xi][h * 8]);
            const unsigned long long* s2 = reinterpret_cast<const unsigned long long*>(&v);
            d[0] = s2[0]; d[1] = s2[1];
            if (lane < 4) {                 // x-halo chunks xi = 32, 33
                const int xi2 = 32 + (lane >> 1);
                const int gx2 = x0 - 1 + xi2;
                int4 v2; v2.x = v2.y = v2.z = v2.w = 0;
                if (rowok && gx2 < WW)
                    v2 = *reinterpret_cast<const int4*>(
                        xb + (((cb * HH + yy) * WW + gx2) << 4) + h * 8);
                unsigned long long* d2 = reinterpret_cast<unsigned long long*>(&Xt[rr][xi2][h * 8]);
                const unsigned long long* s3 = reinterpret_cast<const unsigned long long*>(&v2);
                d2[0] = s3[0]; d2[1] = s3[1];
            }
        }
        __syncthreads();

        // ---- 9 taps x (2x4 MFMA outer product), K=16 per mfma
        #pragma unroll
        for (int rr = 0; rr < 3; ++rr) {
            #pragma unroll
            for (int s = 0; s < 3; ++s) {
                const int tap = rr * 3 + s;
                const bf16x8 a0 = ldsfrag(&Wlds[tap][wm * 64 + 0 + ln31][lh8]);
                const bf16x8 a1 = ldsfrag(&Wlds[tap][wm * 64 + 32 + ln31][lh8]);
                #pragma unroll
                for (int j = 0; j < 4; ++j) {
                    const bf16x8 b = ldsfrag(&Xt[wn * 4 + j + rr][s + ln31][lh8]);
                    acc[0][j] = __builtin_amdgcn_mfma_f32_32x32x16_bf16(a0, b, acc[0][j], 0, 0, 0);
                    acc[1][j] = __builtin_amdgcn_mfma_f32_32x32x16_bf16(a1, b, acc[1][j], 0, 0, 0);
                }
            }
        }
        __syncthreads();
    }

    // ---- epilogue: C/D map col=lane&31, row=(reg&3)+8*(reg>>2)+4*(lane>>5)
    #pragma unroll
    for (int i = 0; i < 2; ++i) {
        const int mb = k0 + wm * 64 + i * 32 + (lane >> 5) * 4;
        #pragma unroll
        for (int j = 0; j < 4; ++j) {
            const long long py = y0 + wn * 4 + j;
            const long long px = x0 + ln31;
            #pragma unroll
            for (int r = 0; r < 16; ++r) {
                const int m = mb + (r & 3) + 8 * (r >> 2);
                out[((long long)m * HH + py) * WW + px] = acc[i][j][r];
            }
        }
    }
}

// ============ OLD PATH (verified, 1837us) — fallback if ws too small for xb ============
__global__ void wt_transform(const float* __restrict__ w, unsigned short* __restrict__ wt) {
    int idx = blockIdx.x * 256 + threadIdx.x;   // [0, 9*65536)
    int tap = idx >> 16;
    int rem = idx & 65535;
    int k = rem >> 8, c = rem & 255;
    wt[idx] = f2bf(w[((k << 8) | c) * 9 + tap]);
}

__global__ __launch_bounds__(256, 3)
void conv_mfma(const float* __restrict__ x, const unsigned short* __restrict__ wt,
               float* __restrict__ out) {
    __shared__ unsigned short Wlds[9][MT][CPAD];
    __shared__ unsigned short Xto[4 + 2][TX + 2][CPAD];

    const int bid = blockIdx.x;
    const int k0 = (bid & 1) * MT;
    const int tile = bid >> 1;
    const int x0 = (tile & 15) * TX;
    const int y0 = (tile >> 4) * 4;

    const int tid = threadIdx.x;
    const int lane = tid & 63;
    const int wave = tid >> 6;
    const int wm = wave & 1;
    const int wn = wave >> 1;
    const int ln31 = lane & 31;
    const int lh8 = (lane >> 5) * 8;

    f32x16 acc[2][2];
    #pragma unroll
    for (int i = 0; i < 2; ++i)
        #pragma unroll
        for (int j = 0; j < 2; ++j)
            #pragma unroll
            for (int r = 0; r < 16; ++r) acc[i][j][r] = 0.f;

    for (int cb = 0; cb < CIN / BC; ++cb) {
        const int c0 = cb * BC;
        for (int e = tid; e < 9 * MT; e += 256) {
            const int tap = e >> 7;
            const int k = e & (MT - 1);
            const unsigned long long* src = reinterpret_cast<const unsigned long long*>(
                wt + ((tap * COUT + (k0 + k)) * CIN + c0));
            unsigned long long* dst = reinterpret_cast<unsigned long long*>(&Wlds[tap][k][0]);
            dst[0] = src[0]; dst[1] = src[1]; dst[2] = src[2]; dst[3] = src[3];
        }
        {
            const int rowid = tid >> 5, lx = tid & 31;
            for (int p = rowid; p < 6 * BC; p += 8) {
                const int rr = p >> 4, c = p & 15;
                const int yy = y0 - 1 + rr;
                const bool rowok = ((unsigned)yy < (unsigned)HH);
                const float* xrow = x + (long long)(c0 + c) * (HH * WW) + (long long)yy * WW;
                const int gx = x0 - 1 + lx;
                float v0 = (rowok && (unsigned)gx < (unsigned)WW) ? xrow[gx] : 0.f;
                Xto[rr][lx][c] = f2bf(v0);
                if (lx < 2) {
                    const int gx2 = x0 + 31 + lx;
                    float v1 = (rowok && gx2 < WW) ? xrow[gx2] : 0.f;
                    Xto[rr][32 + lx][c] = f2bf(v1);
                }
            }
        }
        __syncthreads();
        #pragma unroll
        for (int rr = 0; rr < 3; ++rr) {
            #pragma unroll
            for (int s = 0; s < 3; ++s) {
                const int tap = rr * 3 + s;
                bf16x8 a0 = ldsfrag(&Wlds[tap][wm * 64 + 0 + ln31][lh8]);
                bf16x8 a1 = ldsfrag(&Wlds[tap][wm * 64 + 32 + ln31][lh8]);
                bf16x8 b0 = ldsfrag(&Xto[wn * 2 + 0 + rr][s + ln31][lh8]);
                bf16x8 b1 = ldsfrag(&Xto[wn * 2 + 1 + rr][s + ln31][lh8]);
                acc[0][0] = __builtin_amdgcn_mfma_f32_32x32x16_bf16(a0, b0, acc[0][0], 0, 0, 0);
                acc[0][1] = __builtin_amdgcn_mfma_f32_32x32x16_bf16(a0, b1, acc[0][1], 0, 0, 0);
                acc[1][0] = __builtin_amdgcn_mfma_f32_32x32x16_bf16(a1, b0, acc[1][0], 0, 0, 0);
                acc[1][1] = __builtin_amdgcn_mfma_f32_32x32x16_bf16(a1, b1, acc[1][1], 0, 0, 0);
            }
        }
        __syncthreads();
    }

    #pragma unroll
    for (int i = 0; i < 2; ++i) {
        const int mb = k0 + wm * 64 + i * 32 + (lane >> 5) * 4;
        #pragma unroll
        for (int j = 0; j < 2; ++j) {
            const long long py = y0 + wn * 2 + j;
            const long long px = x0 + ln31;
            #pragma unroll
            for (int r = 0; r < 16; ++r) {
                const int m = mb + (r & 3) + 8 * (r >> 2);
                out[((long long)m * HH + py) * WW + px] = acc[i][j][r];
            }
        }
    }
}

__global__ void conv_naive(const float* __restrict__ x, const float* __restrict__ w,
                           float* __restrict__ out) {
    const int k = blockIdx.x;
    const int y = blockIdx.y;
    const int xx = blockIdx.z * 256 + threadIdx.x;
    float a = 0.f;
    for (int c = 0; c < CIN; ++c) {
        const float* wp = w + ((k * CIN + c) * 9);
        const float* xp = x + (long long)c * HH * WW;
        #pragma unroll
        for (int r = 0; r < 3; ++r) {
            const int yy = y + r - 1;
            if ((unsigned)yy >= (unsigned)HH) continue;
            const float* row = xp + (long long)yy * WW;
            #pragma unroll
            for (int s = 0; s < 3; ++s) {
                const int gx = xx + s - 1;
                const float v = ((unsigned)gx < (unsigned)WW) ? row[gx] : 0.f;
                a += wp[r * 3 + s] * v;
            }
        }
    }
    out[((long long)k * HH + y) * WW + xx] = a;
}

extern "C" void kernel_launch(void* const* d_in, const int* in_sizes, int n_in,
                              void* d_out, int out_size, void* d_ws, size_t ws_size,
                              hipStream_t stream) {
    const float* x = (const float*)d_in[0];
    const float* w = (const float*)d_in[1];
    float* out = (float*)d_out;

    const size_t xb_bytes  = (size_t)NCB * HH * WW * BC * sizeof(unsigned short);  // 128 MiB
    const size_t wt2_bytes = (size_t)144 * 4096 * sizeof(unsigned short);          // 1.125 MiB
    const size_t wt_bytes  = (size_t)9 * 256 * 256 * sizeof(unsigned short);

    if (ws_size >= xb_bytes + wt2_bytes) {
        unsigned short* xb  = (unsigned short*)d_ws;
        unsigned short* wt2 = (unsigned short*)d_ws + xb_bytes / sizeof(unsigned short);
        x_transform<<<4096, 256, 0, stream>>>(x, xb);       // rebuild every call (ws re-poisoned)
        wt_transform2<<<144, 256, 0, stream>>>(w, wt2);
        conv_mfma2<<<2048, 256, 0, stream>>>(xb, wt2, out);
    } else if (ws_size >= wt_bytes) {
        unsigned short* wt = (unsigned short*)d_ws;
        wt_transform<<<2304, 256, 0, stream>>>(w, wt);
        conv_mfma<<<4096, 256, 0, stream>>>(x, wt, out);
    } else {
        conv_naive<<<dim3(256, 512, 2), 256, 0, stream>>>(x, w, out);
    }
}

// Round 2
// 692.292 us; speedup vs baseline: 1.1447x; 1.1447x over previous
//
#include <hip/hip_runtime.h>
#include <stdint.h>

typedef __attribute__((ext_vector_type(8))) __bf16 bf16x8;
typedef __attribute__((ext_vector_type(16))) float f32x16;

constexpr int CIN = 256, COUT = 256, HH = 512, WW = 512;
constexpr int BC = 16;           // input channels per K-iteration
constexpr int NCB = CIN / BC;    // 16 channel blocks
constexpr int MT = 128;          // out-channels per workgroup
constexpr int TY = 8, TX = 32;   // pixel tile: 8 rows x 32 cols

__device__ __forceinline__ unsigned short f2bf(float f) {
    union { float f; unsigned int u; } v; v.f = f;
    return (unsigned short)((v.u + 0x7fffu + ((v.u >> 16) & 1u)) >> 16);  // RNE
}

// 16B zero source for OOB staging loads (device .bss -> zero, never written)
__device__ __align__(256) unsigned short g_zero16[16] = {};

// async global->LDS, 16B per lane; LDS dest = wave-uniform base + lane*16
__device__ __forceinline__ void gload16(const void* g, const void* l) {
    __builtin_amdgcn_global_load_lds(
        (const __attribute__((address_space(1))) unsigned int*)g,
        (__attribute__((address_space(3))) unsigned int*)l, 16, 0, 0);
}

// ---------------- weight transform: wt2[cb][tap][k][ci] bf16 ----------------
__global__ void wt_transform2(const float* __restrict__ w, unsigned short* __restrict__ wt2) {
    const int cbtap = blockIdx.x;              // [0, 144)
    const int cb = cbtap / 9, tap = cbtap - cb * 9;
    #pragma unroll 4
    for (int e = threadIdx.x; e < 4096; e += 256) {
        const int k = e >> 4, ci = e & 15;
        wt2[cbtap * 4096 + e] = f2bf(w[(k * CIN + cb * BC + ci) * 9 + tap]);
    }
}

// ---------------- input transform: xb[cb][y][x][ci] bf16 ----------------
// block = (y, 64px chunk, 4-cb group); LDS fp32 [16][72]: b128 writes balanced,
// b32 reads are 4-lane broadcasts (conflict-free); ushort4 coalesced stores.
__global__ __launch_bounds__(256)
void x_transform(const float* __restrict__ x, unsigned short* __restrict__ xb) {
    __shared__ __align__(16) float Xl[16][72];
    const int b   = blockIdx.x;               // 16384 = 512y * 8xc * 4cbg
    const int y   = b >> 5;
    const int xc  = (b >> 2) & 7;
    const int cbg = b & 3;
    const int x0  = xc * 64;
    const int tid = threadIdx.x;
    const int ci  = tid >> 4, p4 = (tid & 15) << 2;   // load mapping
    const int px  = tid >> 2, cig = tid & 3;          // store mapping
    #pragma unroll 1
    for (int g = 0; g < 4; ++g) {
        const int cb = cbg * 4 + g;
        const float4 v = *reinterpret_cast<const float4*>(
            x + ((long long)(cb * 16 + ci) * HH + y) * WW + x0 + p4);
        *reinterpret_cast<float4*>(&Xl[ci][p4]) = v;
        __syncthreads();
        ushort4 o;
        o.x = f2bf(Xl[cig * 4 + 0][px]);
        o.y = f2bf(Xl[cig * 4 + 1][px]);
        o.z = f2bf(Xl[cig * 4 + 2][px]);
        o.w = f2bf(Xl[cig * 4 + 3][px]);
        *reinterpret_cast<ushort4*>(
            xb + (((long long)cb * HH + y) * WW + x0 + px) * 16 + cig * 4) = o;
        __syncthreads();
    }
}

// ---------------- main conv kernel ----------------
__global__ __launch_bounds__(256, 2)
void conv_mfma3(const unsigned short* __restrict__ xb, const unsigned short* __restrict__ wt2,
                float* __restrict__ out) {
    // Linear rows (global_load_lds requires contiguous dest).
    // Wl row = 32B, Xs row-chunk = 32B: b128 frag reads are balanced 8-access/bank.
    __shared__ __align__(16) unsigned short Wl[9][MT][16];        // 36864 B
    __shared__ __align__(16) unsigned short Xs[TY + 2][36][16];   // 11520 B

    const int bid = blockIdx.x;
    // XCD-bijective swizzle (2048 % 8 == 0): pairs (swz, swz^1) = bids (b, b+8)
    // land on the same XCD -> shared X slab is L2-local.
    const int swz = ((bid & 7) << 8) | (bid >> 3);
    const int k0 = (swz & 1) * MT;
    const int tile = swz >> 1;
    const int x0 = (tile & 15) * TX;
    const int y0 = (tile >> 4) * TY;

    const int tid = threadIdx.x;
    const int lane = tid & 63;
    const int wave = tid >> 6;
    const int wm = wave & 1;
    const int wn = wave >> 1;
    const int ln31 = lane & 31;
    const int lh8 = (lane >> 5) * 8;

    f32x16 acc[2][4];
    #pragma unroll
    for (int i = 0; i < 2; ++i)
        #pragma unroll
        for (int j = 0; j < 4; ++j)
            #pragma unroll
            for (int r = 0; r < 16; ++r) acc[i][j][r] = 0.f;

    // wave-uniform staging bases
    const unsigned short* wsrc0 = wt2 + (size_t)k0 * 16 + (size_t)tid * 8;
    unsigned short* wl = ((unsigned short*)Wl) + (tid >> 6) * 512;

    // ---- stage cb = 0
    {
        const unsigned short* wsrc = wsrc0;
        #pragma unroll
        for (int i = 0; i < 9; ++i)
            gload16(wsrc + (size_t)i * 4096, wl + i * 2048);
        #pragma unroll
        for (int t = 0; t < 3; ++t) {
            const int rr = wave + t * 4;
            if (rr < TY + 2) {
                const int yy = y0 - 1 + rr;
                const bool rok = (unsigned)yy < (unsigned)HH;
                const size_t rowb = ((size_t)0 * HH + (rok ? yy : 0)) * WW;
                const int gx = x0 - 1 + (lane >> 1);
                const bool ok = rok && ((unsigned)gx < (unsigned)WW);
                const unsigned short* gs = ok ? xb + (rowb + gx) * 16 + (lane & 1) * 8 : g_zero16;
                gload16(gs, &Xs[rr][0][0]);
                if (lane < 8) {
                    const int gx2 = x0 + 31 + (lane >> 1);
                    const bool ok2 = rok && gx2 < WW;
                    const unsigned short* gs2 = ok2 ? xb + (rowb + gx2) * 16 + (lane & 1) * 8 : g_zero16;
                    gload16(gs2, &Xs[rr][32][0]);
                }
            }
        }
        asm volatile("s_waitcnt vmcnt(0)" ::: "memory");
        __builtin_amdgcn_s_barrier();
    }

    for (int cb = 0; cb < NCB; ++cb) {
        // ---- MFMA phase: 9 taps x (2x4 outer product), K=16 each
        #pragma unroll
        for (int s = 0; s < 3; ++s) {
            #pragma unroll
            for (int rr = 0; rr < 3; ++rr) {
                const int tap = rr * 3 + s;
                const bf16x8 a0 = *reinterpret_cast<const bf16x8*>(&Wl[tap][wm * 64 + ln31][lh8]);
                const bf16x8 a1 = *reinterpret_cast<const bf16x8*>(&Wl[tap][wm * 64 + 32 + ln31][lh8]);
                #pragma unroll
                for (int j = 0; j < 4; ++j) {
                    const bf16x8 b = *reinterpret_cast<const bf16x8*>(&Xs[wn * 4 + j + rr][s + ln31][lh8]);
                    acc[0][j] = __builtin_amdgcn_mfma_f32_32x32x16_bf16(a0, b, acc[0][j], 0, 0, 0);
                    acc[1][j] = __builtin_amdgcn_mfma_f32_32x32x16_bf16(a1, b, acc[1][j], 0, 0, 0);
                }
            }
        }

        if (cb + 1 < NCB) {
            const int cn = cb + 1;
            asm volatile("s_waitcnt lgkmcnt(0)" ::: "memory");  // all LDS reads done
            __builtin_amdgcn_s_barrier();
            // ---- stage cb+1 (async direct-to-LDS; latency hidden by the other block)
            const unsigned short* wsrc = wsrc0 + (size_t)cn * 9 * 4096;
            #pragma unroll
            for (int i = 0; i < 9; ++i)
                gload16(wsrc + (size_t)i * 4096, wl + i * 2048);
            #pragma unroll
            for (int t = 0; t < 3; ++t) {
                const int rr = wave + t * 4;
                if (rr < TY + 2) {
                    const int yy = y0 - 1 + rr;
                    const bool rok = (unsigned)yy < (unsigned)HH;
                    const size_t rowb = ((size_t)cn * HH + (rok ? yy : 0)) * WW;
                    const int gx = x0 - 1 + (lane >> 1);
                    const bool ok = rok && ((unsigned)gx < (unsigned)WW);
                    const unsigned short* gs = ok ? xb + (rowb + gx) * 16 + (lane & 1) * 8 : g_zero16;
                    gload16(gs, &Xs[rr][0][0]);
                    if (lane < 8) {
                        const int gx2 = x0 + 31 + (lane >> 1);
                        const bool ok2 = rok && gx2 < WW;
                        const unsigned short* gs2 = ok2 ? xb + (rowb + gx2) * 16 + (lane & 1) * 8 : g_zero16;
                        gload16(gs2, &Xs[rr][32][0]);
                    }
                }
            }
            asm volatile("s_waitcnt vmcnt(0)" ::: "memory");    // LDS populated
            __builtin_amdgcn_s_barrier();
        }
    }

    // ---- epilogue: C/D map col=lane&31, row=(reg&3)+8*(reg>>2)+4*(lane>>5)
    #pragma unroll
    for (int i = 0; i < 2; ++i) {
        const int mb = k0 + wm * 64 + i * 32 + (lane >> 5) * 4;
        #pragma unroll
        for (int j = 0; j < 4; ++j) {
            const long long py = y0 + wn * 4 + j;
            const long long px = x0 + ln31;
            #pragma unroll
            for (int r = 0; r < 16; ++r) {
                const int m = mb + (r & 3) + 8 * (r >> 2);
                out[((long long)m * HH + py) * WW + px] = acc[i][j][r];
            }
        }
    }
}

// ---------------- safety fallback (ws too small) ----------------
__global__ void conv_naive(const float* __restrict__ x, const float* __restrict__ w,
                           float* __restrict__ out) {
    const int k = blockIdx.x;
    const int y = blockIdx.y;
    const int xx = blockIdx.z * 256 + threadIdx.x;
    float a = 0.f;
    for (int c = 0; c < CIN; ++c) {
        const float* wp = w + ((k * CIN + c) * 9);
        const float* xp = x + (long long)c * HH * WW;
        #pragma unroll
        for (int r = 0; r < 3; ++r) {
            const int yy = y + r - 1;
            if ((unsigned)yy >= (unsigned)HH) continue;
            const float* row = xp + (long long)yy * WW;
            #pragma unroll
            for (int s = 0; s < 3; ++s) {
                const int gx = xx + s - 1;
                const float v = ((unsigned)gx < (unsigned)WW) ? row[gx] : 0.f;
                a += wp[r * 3 + s] * v;
            }
        }
    }
    out[((long long)k * HH + y) * WW + xx] = a;
}

extern "C" void kernel_launch(void* const* d_in, const int* in_sizes, int n_in,
                              void* d_out, int out_size, void* d_ws, size_t ws_size,
                              hipStream_t stream) {
    const float* x = (const float*)d_in[0];
    const float* w = (const float*)d_in[1];
    float* out = (float*)d_out;

    const size_t xb_bytes  = (size_t)NCB * HH * WW * BC * sizeof(unsigned short);  // 128 MiB
    const size_t wt2_bytes = (size_t)144 * 4096 * sizeof(unsigned short);          // 1.125 MiB

    if (ws_size >= xb_bytes + wt2_bytes) {
        unsigned short* xb  = (unsigned short*)d_ws;
        unsigned short* wt2 = (unsigned short*)d_ws + xb_bytes / sizeof(unsigned short);
        x_transform<<<16384, 256, 0, stream>>>(x, xb);      // rebuild every call (ws re-poisoned)
        wt_transform2<<<144, 256, 0, stream>>>(w, wt2);
        conv_mfma3<<<2048, 256, 0, stream>>>(xb, wt2, out);
    } else {
        conv_naive<<<dim3(256, 512, 2), 256, 0, stream>>>(x, w, out);
    }
}